// Round 1
// baseline (239.002 us; speedup 1.0000x reference)
//
#include <hip/hip_runtime.h>
#include <math.h>

#define DCH 256      // d_model
#define BSZ 512      // graphs
#define NPG 200      // nodes per graph
#define G4  1024     // 4*D (gates)
#define K2  512      // 2*D

__device__ __forceinline__ float sigf(float x) { return 1.0f / (1.0f + __expf(-x)); }

// ---------------------------------------------------------------------------
// prep: Wcat[n,k] = W_ih[n,k] + (k<256 ? W_hh[n,k] : 0);  bsum = b_ih + b_hh;
//       zero the c buffer.
// ---------------------------------------------------------------------------
__global__ __launch_bounds__(256) void prep_kernel(
    const float* __restrict__ W_ih, const float* __restrict__ W_hh,
    const float* __restrict__ b_ih, const float* __restrict__ b_hh,
    float* __restrict__ Wcat, float* __restrict__ bsum, float* __restrict__ cbuf)
{
    const int NW = G4 * K2;            // 524288
    const int NB = G4;                 // 1024
    const int NC = BSZ * DCH;          // 131072
    const int total = NW + NB + NC;
    const int stride = gridDim.x * blockDim.x;
    for (int idx = blockIdx.x * blockDim.x + threadIdx.x; idx < total; idx += stride) {
        if (idx < NW) {
            const int n = idx >> 9, k = idx & 511;
            float v = W_ih[idx];
            if (k < DCH) v += W_hh[n * DCH + k];
            Wcat[idx] = v;
        } else if (idx < NW + NB) {
            const int n = idx - NW;
            bsum[n] = b_ih[n] + b_hh[n];
        } else {
            cbuf[idx - NW - NB] = 0.0f;
        }
    }
}

// ---------------------------------------------------------------------------
// Generic NT GEMM: C[m,n] = sum_k A[m*K+k]*B[n*K+k] + bias[n]
// BM=BN=64, BK=32, 256 threads, 4x4 micro-tile. M,N % 64 == 0, K % 32 == 0.
// ---------------------------------------------------------------------------
template<int BM, int BN, int BK>
__global__ __launch_bounds__(256) void gemm_nt(
    const float* __restrict__ A, const float* __restrict__ Bm,
    const float* __restrict__ bias, float* __restrict__ C,
    int M, int N, int K)
{
    constexpr int PAD = 4;
    __shared__ float As[BK][BM + PAD];   // transposed: As[k][m]
    __shared__ float Bs[BK][BN + PAD];
    const int tid = threadIdx.x;
    const int bm = blockIdx.y * BM, bn = blockIdx.x * BN;
    const int tx = tid & 15, ty = tid >> 4;
    float acc[4][4] = {};

    for (int k0 = 0; k0 < K; k0 += BK) {
        #pragma unroll
        for (int i = 0; i < (BM * BK) / (256 * 4); ++i) {
            const int id = tid + i * 256;       // float4 id
            const int r  = id >> 3;             // BK/4 = 8 float4 per row
            const int cc = id & 7;
            const float4 v = *(const float4*)(A  + (size_t)(bm + r) * K + k0 + 4 * cc);
            As[4*cc+0][r] = v.x; As[4*cc+1][r] = v.y; As[4*cc+2][r] = v.z; As[4*cc+3][r] = v.w;
            const float4 u = *(const float4*)(Bm + (size_t)(bn + r) * K + k0 + 4 * cc);
            Bs[4*cc+0][r] = u.x; Bs[4*cc+1][r] = u.y; Bs[4*cc+2][r] = u.z; Bs[4*cc+3][r] = u.w;
        }
        __syncthreads();
        #pragma unroll
        for (int kk = 0; kk < BK; ++kk) {
            const float4 a4 = *(const float4*)(&As[kk][4 * ty]);
            const float4 b4 = *(const float4*)(&Bs[kk][4 * tx]);
            acc[0][0] += a4.x * b4.x; acc[0][1] += a4.x * b4.y; acc[0][2] += a4.x * b4.z; acc[0][3] += a4.x * b4.w;
            acc[1][0] += a4.y * b4.x; acc[1][1] += a4.y * b4.y; acc[1][2] += a4.y * b4.z; acc[1][3] += a4.y * b4.w;
            acc[2][0] += a4.z * b4.x; acc[2][1] += a4.z * b4.y; acc[2][2] += a4.z * b4.z; acc[2][3] += a4.z * b4.w;
            acc[3][0] += a4.w * b4.x; acc[3][1] += a4.w * b4.y; acc[3][2] += a4.w * b4.z; acc[3][3] += a4.w * b4.w;
        }
        __syncthreads();
    }

    const float4 bv = *(const float4*)(bias + bn + 4 * tx);
    #pragma unroll
    for (int i = 0; i < 4; ++i) {
        float4 o;
        o.x = acc[i][0] + bv.x; o.y = acc[i][1] + bv.y;
        o.z = acc[i][2] + bv.z; o.w = acc[i][3] + bv.w;
        *(float4*)(C + (size_t)(bm + 4 * ty + i) * N + bn + 4 * tx) = o;
    }
}

// ---------------------------------------------------------------------------
// Fused LSTM cell + online-softmax attention. One block per graph, 256 thr.
// Writes h into hr[b][0:256], r into hr[b][256:512], updates c.
// ---------------------------------------------------------------------------
__global__ __launch_bounds__(256) void lstm_attn_kernel(
    const float* __restrict__ gates, const float* __restrict__ bsum,
    const float* __restrict__ node, const int* __restrict__ node_num,
    float* __restrict__ cbuf, float* __restrict__ hr, int first)
{
    const int b = blockIdx.x;
    const int t = threadIdx.x;
    __shared__ float qs[DCH];
    __shared__ float red_r[4][DCH];
    __shared__ float red_m[4], red_s[4];

    // ---- LSTM cell (torch gate order i,f,g,o) ----
    float gi, gf, gg, go;
    if (first) {
        gi = bsum[t]; gf = bsum[DCH + t]; gg = bsum[2 * DCH + t]; go = bsum[3 * DCH + t];
    } else {
        const float* gr = gates + (size_t)b * G4;
        gi = gr[t]; gf = gr[DCH + t]; gg = gr[2 * DCH + t]; go = gr[3 * DCH + t];
    }
    const float c_old = first ? 0.0f : cbuf[b * DCH + t];
    const float cn = sigf(gf) * c_old + sigf(gi) * tanhf(gg);
    const float hn = sigf(go) * tanhf(cn);
    cbuf[b * DCH + t] = cn;
    hr[(size_t)b * K2 + t] = hn;
    qs[t] = hn;
    __syncthreads();

    // ---- online softmax attention: one wave handles nodes n ≡ w (mod 4) ----
    const int w = t >> 6, l = t & 63;
    const float4 q4 = *(const float4*)(qs + 4 * l);
    const int cnt = node_num[b];
    const float* nb = node + (size_t)b * NPG * DCH;

    float m = -INFINITY, s = 0.0f;
    float4 racc = make_float4(0.f, 0.f, 0.f, 0.f);

    float4 x = make_float4(0.f, 0.f, 0.f, 0.f);
    if (w < cnt) x = *(const float4*)(nb + (size_t)w * DCH + 4 * l);
    for (int n = w; n < cnt; n += 4) {
        const int np = n + 4;
        float4 xn = make_float4(0.f, 0.f, 0.f, 0.f);
        if (np < cnt) xn = *(const float4*)(nb + (size_t)np * DCH + 4 * l);  // prefetch
        float p = x.x * q4.x + x.y * q4.y + x.z * q4.z + x.w * q4.w;
        #pragma unroll
        for (int off = 32; off > 0; off >>= 1) p += __shfl_xor(p, off);
        const float mn = fmaxf(m, p);
        const float sc = __expf(m - mn);
        const float wn = __expf(p - mn);
        s = s * sc + wn;
        racc.x = racc.x * sc + wn * x.x;
        racc.y = racc.y * sc + wn * x.y;
        racc.z = racc.z * sc + wn * x.z;
        racc.w = racc.w * sc + wn * x.w;
        m = mn;
        x = xn;
    }
    *(float4*)(&red_r[w][4 * l]) = racc;
    if (l == 0) { red_m[w] = m; red_s[w] = s; }
    __syncthreads();

    // ---- merge 4 wave partials; thread t owns output dim t ----
    const float M = fmaxf(fmaxf(red_m[0], red_m[1]), fmaxf(red_m[2], red_m[3]));
    float stot = 0.0f, rtot = 0.0f;
    #pragma unroll
    for (int ww = 0; ww < 4; ++ww) {
        const float sc = __expf(red_m[ww] - M);
        stot += sc * red_s[ww];
        rtot += sc * red_r[ww][t];
    }
    hr[(size_t)b * K2 + DCH + t] = rtot / (stot + 1e-6f);
}

// ---------------------------------------------------------------------------
extern "C" void kernel_launch(void* const* d_in, const int* in_sizes, int n_in,
                              void* d_out, int out_size, void* d_ws, size_t ws_size,
                              hipStream_t stream)
{
    const float* node     = (const float*)d_in[0];
    const int*   node_num = (const int*)  d_in[1];
    const float* W_ih     = (const float*)d_in[2];
    const float* W_hh     = (const float*)d_in[3];
    const float* b_ih     = (const float*)d_in[4];
    const float* b_hh     = (const float*)d_in[5];
    const float* Wo       = (const float*)d_in[6];
    const float* bo       = (const float*)d_in[7];
    float* out = (float*)d_out;

    float* ws    = (float*)d_ws;
    float* Wcat  = ws;                       // 1024*512
    float* bsum  = Wcat + G4 * K2;           // 1024
    float* cbuf  = bsum + G4;                // 512*256
    float* hr    = cbuf + BSZ * DCH;         // 512*512
    float* gates = hr + BSZ * K2;            // 512*1024

    prep_kernel<<<1024, 256, 0, stream>>>(W_ih, W_hh, b_ih, b_hh, Wcat, bsum, cbuf);

    // step 1: h=c=q_star=0 -> gates = bsum
    lstm_attn_kernel<<<BSZ, 256, 0, stream>>>(nullptr, bsum, node, node_num, cbuf, hr, 1);

    for (int s = 1; s < 4; ++s) {
        gemm_nt<64, 64, 32><<<dim3(G4 / 64, BSZ / 64), 256, 0, stream>>>(
            hr, Wcat, bsum, gates, BSZ, G4, K2);
        lstm_attn_kernel<<<BSZ, 256, 0, stream>>>(gates, bsum, node, node_num, cbuf, hr, 0);
    }

    // out = hr @ Wo^T + bo   (M=512, N=256, K=512)
    gemm_nt<64, 64, 32><<<dim3(DCH / 64, BSZ / 64), 256, 0, stream>>>(
        hr, Wo, bo, out, BSZ, DCH, K2);
}

// Round 2
// 143.352 us; speedup vs baseline: 1.6672x; 1.6672x over previous
//
#include <hip/hip_runtime.h>
#include <math.h>

#define DCH 256      // d_model
#define BSZ 512      // graphs
#define NPG 200      // nodes per graph
#define G4  1024     // 4*D (gates)
#define K2  512      // 2*D

__device__ __forceinline__ float sigf(float x) { return 1.0f / (1.0f + __expf(-x)); }

// ---------------------------------------------------------------------------
// prep: Wcat[n,k] = W_ih[n,k] + (k<256 ? W_hh[n,k] : 0);  bsum = b_ih + b_hh
// ---------------------------------------------------------------------------
__global__ __launch_bounds__(256) void prep_kernel(
    const float* __restrict__ W_ih, const float* __restrict__ W_hh,
    const float* __restrict__ b_ih, const float* __restrict__ b_hh,
    float* __restrict__ Wcat, float* __restrict__ bsum)
{
    const int NW = G4 * K2;            // 524288
    const int NB = G4;                 // 1024
    const int total = NW + NB;
    const int stride = gridDim.x * blockDim.x;
    for (int idx = blockIdx.x * blockDim.x + threadIdx.x; idx < total; idx += stride) {
        if (idx < NW) {
            const int n = idx >> 9, k = idx & 511;
            float v = W_ih[idx];
            if (k < DCH) v += W_hh[n * DCH + k];
            Wcat[idx] = v;
        } else {
            const int n = idx - NW;
            bsum[n] = b_ih[n] + b_hh[n];
        }
    }
}

// ---------------------------------------------------------------------------
// NT GEMM partial: Cpart[ks][m,n] = sum_{k in ks-slice} A[m*K+k]*B[n*K+k]
// BM=BN=64, BK=32, 256 threads, 4x4 micro-tile. blockIdx.z = k-slice.
// ---------------------------------------------------------------------------
template<int BM, int BN, int BK>
__global__ __launch_bounds__(256) void gemm_nt_part(
    const float* __restrict__ A, const float* __restrict__ Bm,
    float* __restrict__ Cpart, int M, int N, int K, int Kper)
{
    constexpr int PAD = 4;
    __shared__ __align__(16) float As[BK][BM + PAD];   // transposed: As[k][m]
    __shared__ __align__(16) float Bs[BK][BN + PAD];
    const int tid = threadIdx.x;
    const int bm = blockIdx.y * BM, bn = blockIdx.x * BN;
    const int kbase = blockIdx.z * Kper;
    const int tx = tid & 15, ty = tid >> 4;
    float acc[4][4] = {};

    for (int k0 = 0; k0 < Kper; k0 += BK) {
        #pragma unroll
        for (int i = 0; i < (BM * BK) / (256 * 4); ++i) {
            const int id = tid + i * 256;       // float4 id
            const int r  = id >> 3;             // 8 float4 per row of BK
            const int cc = id & 7;
            const float4 v = *(const float4*)(A  + (size_t)(bm + r) * K + kbase + k0 + 4 * cc);
            As[4*cc+0][r] = v.x; As[4*cc+1][r] = v.y; As[4*cc+2][r] = v.z; As[4*cc+3][r] = v.w;
            const float4 u = *(const float4*)(Bm + (size_t)(bn + r) * K + kbase + k0 + 4 * cc);
            Bs[4*cc+0][r] = u.x; Bs[4*cc+1][r] = u.y; Bs[4*cc+2][r] = u.z; Bs[4*cc+3][r] = u.w;
        }
        __syncthreads();
        #pragma unroll
        for (int kk = 0; kk < BK; ++kk) {
            const float4 a4 = *(const float4*)(&As[kk][4 * ty]);
            const float4 b4 = *(const float4*)(&Bs[kk][4 * tx]);
            acc[0][0] += a4.x * b4.x; acc[0][1] += a4.x * b4.y; acc[0][2] += a4.x * b4.z; acc[0][3] += a4.x * b4.w;
            acc[1][0] += a4.y * b4.x; acc[1][1] += a4.y * b4.y; acc[1][2] += a4.y * b4.z; acc[1][3] += a4.y * b4.w;
            acc[2][0] += a4.z * b4.x; acc[2][1] += a4.z * b4.y; acc[2][2] += a4.z * b4.z; acc[2][3] += a4.z * b4.w;
            acc[3][0] += a4.w * b4.x; acc[3][1] += a4.w * b4.y; acc[3][2] += a4.w * b4.z; acc[3][3] += a4.w * b4.w;
        }
        __syncthreads();
    }

    float* Cp = Cpart + (size_t)blockIdx.z * M * N;
    #pragma unroll
    for (int i = 0; i < 4; ++i) {
        float4 o;
        o.x = acc[i][0]; o.y = acc[i][1]; o.z = acc[i][2]; o.w = acc[i][3];
        *(float4*)(Cp + (size_t)(bm + 4 * ty + i) * N + bn + 4 * tx) = o;
    }
}

// ---------------------------------------------------------------------------
// finalize: out = opart[0]+opart[1]+opart[2]+opart[3] + bo  (float4-wide)
// ---------------------------------------------------------------------------
__global__ __launch_bounds__(256) void finalize_kernel(
    const float* __restrict__ opart, const float* __restrict__ bo,
    float* __restrict__ out)
{
    const int i = blockIdx.x * blockDim.x + threadIdx.x;   // float4 id, 32768 total
    const int NQ = BSZ * DCH / 4;
    if (i >= NQ) return;
    const float4* p0 = (const float4*)opart;
    const float4* p1 = p0 + NQ;
    const float4* p2 = p1 + NQ;
    const float4* p3 = p2 + NQ;
    const float4 b4 = *((const float4*)bo + (i & 63));
    float4 a = p0[i], b = p1[i], c = p2[i], d = p3[i], o;
    o.x = a.x + b.x + c.x + d.x + b4.x;
    o.y = a.y + b.y + c.y + d.y + b4.y;
    o.z = a.z + b.z + c.z + d.z + b4.z;
    o.w = a.w + b.w + c.w + d.w + b4.w;
    ((float4*)out)[i] = o;
}

// ---------------------------------------------------------------------------
// Fused LSTM cell + online-softmax attention, 16-lane-cluster layout.
// One block per graph, 256 threads = 4 waves = 16 clusters.
// Cluster g handles nodes {it*32 + 2g, it*32 + 2g + 1}. Lane p of a cluster
// owns dims j*64 + p*4 .. +3 (j=0..3) -> 256B coalesced loads per cluster.
// ---------------------------------------------------------------------------
__global__ __launch_bounds__(256) void lstm_attn_kernel(
    const float* __restrict__ gpart,   // [2][BSZ][G4] partials (ignored if first)
    const float* __restrict__ bsum,
    const float* __restrict__ node, const int* __restrict__ node_num,
    float* __restrict__ cbuf, float* __restrict__ hr, int first)
{
    const int b = blockIdx.x;
    const int t = threadIdx.x;
    __shared__ __align__(16) float qs[DCH];
    __shared__ __align__(16) float red_r[16][DCH];
    __shared__ float red_m[16], red_s[16];

    // ---- LSTM cell (torch gate order i,f,g,o) ----
    float gi, gf, gg, go;
    if (first) {
        gi = bsum[t]; gf = bsum[DCH + t]; gg = bsum[2 * DCH + t]; go = bsum[3 * DCH + t];
    } else {
        const float* g0 = gpart + (size_t)b * G4;
        const float* g1 = gpart + (size_t)BSZ * G4 + (size_t)b * G4;
        gi = g0[t]           + g1[t]           + bsum[t];
        gf = g0[DCH + t]     + g1[DCH + t]     + bsum[DCH + t];
        gg = g0[2 * DCH + t] + g1[2 * DCH + t] + bsum[2 * DCH + t];
        go = g0[3 * DCH + t] + g1[3 * DCH + t] + bsum[3 * DCH + t];
    }
    const float c_old = first ? 0.0f : cbuf[b * DCH + t];
    const float cn = sigf(gf) * c_old + sigf(gi) * tanhf(gg);
    const float hn = sigf(go) * tanhf(cn);
    cbuf[b * DCH + t] = cn;
    hr[(size_t)b * K2 + t] = hn;
    qs[t] = hn;
    __syncthreads();

    // ---- attention ----
    const int w = t >> 6, l = t & 63;
    const int p = l & 15;              // pos in cluster
    const int g = w * 4 + (l >> 4);    // cluster id 0..15
    const int cnt = node_num[b];
    const float* nb = node + (size_t)b * NPG * DCH;

    float4 qv[4];
    #pragma unroll
    for (int j = 0; j < 4; ++j) qv[j] = *(const float4*)(qs + j * 64 + p * 4);

    float m = -INFINITY, s = 0.0f;
    float4 racc[4] = {};

    const int nit = (cnt + 31) >> 5;

    float4 x0[4], x1[4];
    {
        const int n0 = 2 * g;
        #pragma unroll
        for (int j = 0; j < 4; ++j) {
            x0[j] = (n0     < cnt) ? *(const float4*)(nb + (size_t)n0 * DCH + j * 64 + p * 4)
                                   : make_float4(0.f, 0.f, 0.f, 0.f);
            x1[j] = (n0 + 1 < cnt) ? *(const float4*)(nb + (size_t)(n0 + 1) * DCH + j * 64 + p * 4)
                                   : make_float4(0.f, 0.f, 0.f, 0.f);
        }
    }

    for (int it = 0; it < nit; ++it) {
        // prefetch next pair
        float4 y0[4], y1[4];
        const int np = (it + 1) * 32 + 2 * g;
        #pragma unroll
        for (int j = 0; j < 4; ++j) {
            y0[j] = (np     < cnt) ? *(const float4*)(nb + (size_t)np * DCH + j * 64 + p * 4)
                                   : make_float4(0.f, 0.f, 0.f, 0.f);
            y1[j] = (np + 1 < cnt) ? *(const float4*)(nb + (size_t)(np + 1) * DCH + j * 64 + p * 4)
                                   : make_float4(0.f, 0.f, 0.f, 0.f);
        }
        // two independent dot products
        float e0 = 0.f, e1 = 0.f;
        #pragma unroll
        for (int j = 0; j < 4; ++j) {
            e0 += x0[j].x * qv[j].x + x0[j].y * qv[j].y + x0[j].z * qv[j].z + x0[j].w * qv[j].w;
            e1 += x1[j].x * qv[j].x + x1[j].y * qv[j].y + x1[j].z * qv[j].z + x1[j].w * qv[j].w;
        }
        // 4-hop reduce within the 16-lane cluster (interleaved chains)
        #pragma unroll
        for (int off = 1; off < 16; off <<= 1) {
            e0 += __shfl_xor(e0, off);
            e1 += __shfl_xor(e1, off);
        }
        const int n0 = it * 32 + 2 * g;
        if (n0     >= cnt) e0 = -INFINITY;
        if (n0 + 1 >= cnt) e1 = -INFINITY;
        const float mn = fmaxf(m, fmaxf(e0, e1));
        if (mn > -INFINITY) {
            const float sc = __expf(m - mn);
            const float w0 = __expf(e0 - mn);
            const float w1 = __expf(e1 - mn);
            s = s * sc + w0 + w1;
            #pragma unroll
            for (int j = 0; j < 4; ++j) {
                racc[j].x = racc[j].x * sc + w0 * x0[j].x + w1 * x1[j].x;
                racc[j].y = racc[j].y * sc + w0 * x0[j].y + w1 * x1[j].y;
                racc[j].z = racc[j].z * sc + w0 * x0[j].z + w1 * x1[j].z;
                racc[j].w = racc[j].w * sc + w0 * x0[j].w + w1 * x1[j].w;
            }
            m = mn;
        }
        #pragma unroll
        for (int j = 0; j < 4; ++j) { x0[j] = y0[j]; x1[j] = y1[j]; }
    }

    // ---- merge 16 cluster partials ----
    #pragma unroll
    for (int j = 0; j < 4; ++j)
        *(float4*)(&red_r[g][j * 64 + p * 4]) = racc[j];
    if (p == 0) { red_m[g] = m; red_s[g] = s; }
    __syncthreads();

    float M = -INFINITY;
    #pragma unroll
    for (int g2 = 0; g2 < 16; ++g2) M = fmaxf(M, red_m[g2]);
    float stot = 0.0f, rtot = 0.0f;
    #pragma unroll
    for (int g2 = 0; g2 < 16; ++g2) {
        const float sc = __expf(red_m[g2] - M);
        stot += sc * red_s[g2];
        rtot += sc * red_r[g2][t];
    }
    hr[(size_t)b * K2 + DCH + t] = rtot / (stot + 1e-6f);
}

// ---------------------------------------------------------------------------
extern "C" void kernel_launch(void* const* d_in, const int* in_sizes, int n_in,
                              void* d_out, int out_size, void* d_ws, size_t ws_size,
                              hipStream_t stream)
{
    const float* node     = (const float*)d_in[0];
    const int*   node_num = (const int*)  d_in[1];
    const float* W_ih     = (const float*)d_in[2];
    const float* W_hh     = (const float*)d_in[3];
    const float* b_ih     = (const float*)d_in[4];
    const float* b_hh     = (const float*)d_in[5];
    const float* Wo       = (const float*)d_in[6];
    const float* bo       = (const float*)d_in[7];
    float* out = (float*)d_out;

    float* ws    = (float*)d_ws;
    float* Wcat  = ws;                        // 1024*512
    float* bsum  = Wcat + G4 * K2;            // 1024
    float* cbuf  = bsum + G4;                 // 512*256
    float* hr    = cbuf + BSZ * DCH;          // 512*512
    float* gpart = hr + BSZ * K2;             // 2*512*1024
    float* opart = gpart + 2 * BSZ * G4;      // 4*512*256

    prep_kernel<<<1024, 256, 0, stream>>>(W_ih, W_hh, b_ih, b_hh, Wcat, bsum);

    // step 1: h=c=q_star=0 -> gates = bsum only
    lstm_attn_kernel<<<BSZ, 256, 0, stream>>>(gpart, bsum, node, node_num, cbuf, hr, 1);

    for (int s = 1; s < 4; ++s) {
        // gates partials: M=512, N=1024, K=512, 2-way k-split -> 256 blocks
        gemm_nt_part<64, 64, 32><<<dim3(G4 / 64, BSZ / 64, 2), 256, 0, stream>>>(
            hr, Wcat, gpart, BSZ, G4, K2, K2 / 2);
        lstm_attn_kernel<<<BSZ, 256, 0, stream>>>(gpart, bsum, node, node_num, cbuf, hr, 0);
    }

    // out partials: M=512, N=256, K=512, 4-way k-split -> 128 blocks
    gemm_nt_part<64, 64, 32><<<dim3(DCH / 64, BSZ / 64, 4), 256, 0, stream>>>(
        hr, Wo, opart, BSZ, DCH, K2, K2 / 4);
    finalize_kernel<<<(BSZ * DCH / 4 + 255) / 256, 256, 0, stream>>>(opart, bo, out);
}

// Round 3
// 134.374 us; speedup vs baseline: 1.7786x; 1.0668x over previous
//
#include <hip/hip_runtime.h>
#include <math.h>

#define DCH 256      // d_model
#define BSZ 512      // graphs
#define NPG 200      // nodes per graph
#define G4  1024     // 4*D (gates)
#define K2  512      // 2*D
#define KSPL 8       // k-split factor for both GEMMs

__device__ __forceinline__ float sigf(float x) { return 1.0f / (1.0f + __expf(-x)); }

// ---------------------------------------------------------------------------
// NT GEMM partial: Cpart[z][m,n] = sum_{k in slice z} A[m*K+k]*Beff[n*K+k]
// Beff = Bm (+ Whh when k<256, if Whh != nullptr).
// BM=BN=64, BK=32, 256 threads, 4x4 micro-tile. blockIdx.z = k-slice.
// ---------------------------------------------------------------------------
template<int BM, int BN, int BK>
__global__ __launch_bounds__(256) void gemm_nt_part(
    const float* __restrict__ A, const float* __restrict__ Bm,
    const float* __restrict__ Whh,          // may be nullptr
    float* __restrict__ Cpart, int M, int N, int K, int Kper)
{
    constexpr int PAD = 4;
    __shared__ __align__(16) float As[BK][BM + PAD];   // transposed: As[k][m]
    __shared__ __align__(16) float Bs[BK][BN + PAD];
    const int tid = threadIdx.x;
    const int bm = blockIdx.y * BM, bn = blockIdx.x * BN;
    const int kbase = blockIdx.z * Kper;
    const int tx = tid & 15, ty = tid >> 4;
    float acc[4][4] = {};

    for (int k0 = 0; k0 < Kper; k0 += BK) {
        const int kg = kbase + k0;                 // uniform over block
        const bool addhh = (Whh != nullptr) && (kg < DCH);
        #pragma unroll
        for (int i = 0; i < (BM * BK) / (256 * 4); ++i) {
            const int id = tid + i * 256;       // float4 id
            const int r  = id >> 3;             // 8 float4 per row of BK
            const int cc = id & 7;
            const float4 v = *(const float4*)(A + (size_t)(bm + r) * K + kg + 4 * cc);
            As[4*cc+0][r] = v.x; As[4*cc+1][r] = v.y; As[4*cc+2][r] = v.z; As[4*cc+3][r] = v.w;
            float4 u = *(const float4*)(Bm + (size_t)(bn + r) * K + kg + 4 * cc);
            if (addhh) {
                const float4 h4 = *(const float4*)(Whh + (size_t)(bn + r) * DCH + kg + 4 * cc);
                u.x += h4.x; u.y += h4.y; u.z += h4.z; u.w += h4.w;
            }
            Bs[4*cc+0][r] = u.x; Bs[4*cc+1][r] = u.y; Bs[4*cc+2][r] = u.z; Bs[4*cc+3][r] = u.w;
        }
        __syncthreads();
        #pragma unroll
        for (int kk = 0; kk < BK; ++kk) {
            const float4 a4 = *(const float4*)(&As[kk][4 * ty]);
            const float4 b4 = *(const float4*)(&Bs[kk][4 * tx]);
            acc[0][0] += a4.x * b4.x; acc[0][1] += a4.x * b4.y; acc[0][2] += a4.x * b4.z; acc[0][3] += a4.x * b4.w;
            acc[1][0] += a4.y * b4.x; acc[1][1] += a4.y * b4.y; acc[1][2] += a4.y * b4.z; acc[1][3] += a4.y * b4.w;
            acc[2][0] += a4.z * b4.x; acc[2][1] += a4.z * b4.y; acc[2][2] += a4.z * b4.z; acc[2][3] += a4.z * b4.w;
            acc[3][0] += a4.w * b4.x; acc[3][1] += a4.w * b4.y; acc[3][2] += a4.w * b4.z; acc[3][3] += a4.w * b4.w;
        }
        __syncthreads();
    }

    float* Cp = Cpart + (size_t)blockIdx.z * M * N;
    #pragma unroll
    for (int i = 0; i < 4; ++i) {
        float4 o;
        o.x = acc[i][0]; o.y = acc[i][1]; o.z = acc[i][2]; o.w = acc[i][3];
        *(float4*)(Cp + (size_t)(bm + 4 * ty + i) * N + bn + 4 * tx) = o;
    }
}

// ---------------------------------------------------------------------------
// finalize: out = sum_z opart[z] + bo  (float4-wide)
// ---------------------------------------------------------------------------
__global__ __launch_bounds__(256) void finalize_kernel(
    const float* __restrict__ opart, const float* __restrict__ bo,
    float* __restrict__ out)
{
    const int i = blockIdx.x * blockDim.x + threadIdx.x;   // float4 id
    const int NQ = BSZ * DCH / 4;
    if (i >= NQ) return;
    const float4 b4 = *((const float4*)bo + (i & 63));
    float4 o = b4;
    #pragma unroll
    for (int z = 0; z < KSPL; ++z) {
        const float4 p = ((const float4*)opart)[(size_t)z * NQ + i];
        o.x += p.x; o.y += p.y; o.z += p.z; o.w += p.w;
    }
    ((float4*)out)[i] = o;
}

// ---------------------------------------------------------------------------
// Fused LSTM cell + online-softmax attention, 16-lane-cluster layout.
// One block per graph, 256 threads = 4 waves = 16 clusters.
// Cluster g handles nodes {it*32 + 2g, it*32 + 2g + 1}. Lane p of a cluster
// owns dims j*64 + p*4 .. +3 (j=0..3) -> 256B coalesced loads per cluster.
// ---------------------------------------------------------------------------
__global__ __launch_bounds__(256) void lstm_attn_kernel(
    const float* __restrict__ gpart,   // [KSPL][BSZ][G4] partials (ignored if first)
    const float* __restrict__ b_ih, const float* __restrict__ b_hh,
    const float* __restrict__ node, const int* __restrict__ node_num,
    float* __restrict__ cbuf, float* __restrict__ hr, int first)
{
    const int b = blockIdx.x;
    const int t = threadIdx.x;
    __shared__ __align__(16) float qs[DCH];
    __shared__ __align__(16) float red_r[16][DCH];
    __shared__ float red_m[16], red_s[16];

    // ---- LSTM cell (torch gate order i,f,g,o) ----
    float gv[4];
    #pragma unroll
    for (int q = 0; q < 4; ++q) {
        const int idx = q * DCH + t;
        float v = b_ih[idx] + b_hh[idx];
        if (!first) {
            #pragma unroll
            for (int z = 0; z < KSPL; ++z)
                v += gpart[(size_t)z * BSZ * G4 + (size_t)b * G4 + idx];
        }
        gv[q] = v;
    }
    const float c_old = first ? 0.0f : cbuf[b * DCH + t];
    const float cn = sigf(gv[1]) * c_old + sigf(gv[0]) * tanhf(gv[2]);
    const float hn = sigf(gv[3]) * tanhf(cn);
    cbuf[b * DCH + t] = cn;
    hr[(size_t)b * K2 + t] = hn;
    qs[t] = hn;
    __syncthreads();

    // ---- attention ----
    const int w = t >> 6, l = t & 63;
    const int p = l & 15;              // pos in cluster
    const int g = w * 4 + (l >> 4);    // cluster id 0..15
    const int cnt = node_num[b];
    const float* nb = node + (size_t)b * NPG * DCH;

    float4 qv[4];
    #pragma unroll
    for (int j = 0; j < 4; ++j) qv[j] = *(const float4*)(qs + j * 64 + p * 4);

    float m = -INFINITY, s = 0.0f;
    float4 racc[4] = {};

    const int nit = (cnt + 31) >> 5;

    float4 x0[4], x1[4];
    {
        const int n0 = 2 * g;
        #pragma unroll
        for (int j = 0; j < 4; ++j) {
            x0[j] = (n0     < cnt) ? *(const float4*)(nb + (size_t)n0 * DCH + j * 64 + p * 4)
                                   : make_float4(0.f, 0.f, 0.f, 0.f);
            x1[j] = (n0 + 1 < cnt) ? *(const float4*)(nb + (size_t)(n0 + 1) * DCH + j * 64 + p * 4)
                                   : make_float4(0.f, 0.f, 0.f, 0.f);
        }
    }

    for (int it = 0; it < nit; ++it) {
        // prefetch next pair
        float4 y0[4], y1[4];
        const int np = (it + 1) * 32 + 2 * g;
        #pragma unroll
        for (int j = 0; j < 4; ++j) {
            y0[j] = (np     < cnt) ? *(const float4*)(nb + (size_t)np * DCH + j * 64 + p * 4)
                                   : make_float4(0.f, 0.f, 0.f, 0.f);
            y1[j] = (np + 1 < cnt) ? *(const float4*)(nb + (size_t)(np + 1) * DCH + j * 64 + p * 4)
                                   : make_float4(0.f, 0.f, 0.f, 0.f);
        }
        // two independent dot products
        float e0 = 0.f, e1 = 0.f;
        #pragma unroll
        for (int j = 0; j < 4; ++j) {
            e0 += x0[j].x * qv[j].x + x0[j].y * qv[j].y + x0[j].z * qv[j].z + x0[j].w * qv[j].w;
            e1 += x1[j].x * qv[j].x + x1[j].y * qv[j].y + x1[j].z * qv[j].z + x1[j].w * qv[j].w;
        }
        // 4-hop reduce within the 16-lane cluster (interleaved chains)
        #pragma unroll
        for (int off = 1; off < 16; off <<= 1) {
            e0 += __shfl_xor(e0, off);
            e1 += __shfl_xor(e1, off);
        }
        const int n0 = it * 32 + 2 * g;
        if (n0     >= cnt) e0 = -INFINITY;
        if (n0 + 1 >= cnt) e1 = -INFINITY;
        const float mn = fmaxf(m, fmaxf(e0, e1));
        if (mn > -INFINITY) {
            const float sc = __expf(m - mn);
            const float w0 = __expf(e0 - mn);
            const float w1 = __expf(e1 - mn);
            s = s * sc + w0 + w1;
            #pragma unroll
            for (int j = 0; j < 4; ++j) {
                racc[j].x = racc[j].x * sc + w0 * x0[j].x + w1 * x1[j].x;
                racc[j].y = racc[j].y * sc + w0 * x0[j].y + w1 * x1[j].y;
                racc[j].z = racc[j].z * sc + w0 * x0[j].z + w1 * x1[j].z;
                racc[j].w = racc[j].w * sc + w0 * x0[j].w + w1 * x1[j].w;
            }
            m = mn;
        }
        #pragma unroll
        for (int j = 0; j < 4; ++j) { x0[j] = y0[j]; x1[j] = y1[j]; }
    }

    // ---- merge 16 cluster partials ----
    #pragma unroll
    for (int j = 0; j < 4; ++j)
        *(float4*)(&red_r[g][j * 64 + p * 4]) = racc[j];
    if (p == 0) { red_m[g] = m; red_s[g] = s; }
    __syncthreads();

    float M = -INFINITY;
    #pragma unroll
    for (int g2 = 0; g2 < 16; ++g2) M = fmaxf(M, red_m[g2]);
    float stot = 0.0f, rtot = 0.0f;
    #pragma unroll
    for (int g2 = 0; g2 < 16; ++g2) {
        const float sc = __expf(red_m[g2] - M);
        stot += sc * red_s[g2];
        rtot += sc * red_r[g2][t];
    }
    hr[(size_t)b * K2 + DCH + t] = rtot / (stot + 1e-6f);
}

// ---------------------------------------------------------------------------
extern "C" void kernel_launch(void* const* d_in, const int* in_sizes, int n_in,
                              void* d_out, int out_size, void* d_ws, size_t ws_size,
                              hipStream_t stream)
{
    const float* node     = (const float*)d_in[0];
    const int*   node_num = (const int*)  d_in[1];
    const float* W_ih     = (const float*)d_in[2];
    const float* W_hh     = (const float*)d_in[3];
    const float* b_ih     = (const float*)d_in[4];
    const float* b_hh     = (const float*)d_in[5];
    const float* Wo       = (const float*)d_in[6];
    const float* bo       = (const float*)d_in[7];
    float* out = (float*)d_out;

    float* ws    = (float*)d_ws;
    float* cbuf  = ws;                        // 512*256
    float* hr    = cbuf + BSZ * DCH;          // 512*512
    float* gpart = hr + BSZ * K2;             // KSPL*512*1024 (16 MB)
    float* opart = gpart + KSPL * BSZ * G4;   // KSPL*512*256  (4 MB)

    // step 1: h=c=q_star=0 -> gates = biases only
    lstm_attn_kernel<<<BSZ, 256, 0, stream>>>(gpart, b_ih, b_hh, node, node_num, cbuf, hr, 1);

    for (int s = 1; s < 4; ++s) {
        // gates partials: M=512, N=1024, K=512, 8-way k-split -> 1024 blocks
        gemm_nt_part<64, 64, 32><<<dim3(G4 / 64, BSZ / 64, KSPL), 256, 0, stream>>>(
            hr, W_ih, W_hh, gpart, BSZ, G4, K2, K2 / KSPL);
        lstm_attn_kernel<<<BSZ, 256, 0, stream>>>(gpart, b_ih, b_hh, node, node_num, cbuf, hr, 0);
    }

    // out partials: M=512, N=256, K=512, 8-way k-split -> 256 blocks
    gemm_nt_part<64, 64, 32><<<dim3(DCH / 64, BSZ / 64, KSPL), 256, 0, stream>>>(
        hr, Wo, nullptr, opart, BSZ, DCH, K2, K2 / KSPL);
    finalize_kernel<<<(BSZ * DCH / 4 + 255) / 256, 256, 0, stream>>>(opart, bo, out);
}